// Round 7
// baseline (223.623 us; speedup 1.0000x reference)
//
#include <hip/hip_runtime.h>
#include <hip/hip_bf16.h>
#include <cmath>

#define D_MODEL 512
#define D_INNER 1024
#define NHEAD 16
#define HDIM 64
#define NSTATE 16
#define NB 8
#define NT 64
#define NW 16
#define MROWS 8192      // NB*NT*NW
#define PROJ_LD 2176    // padded 2096 -> 17*128
#define NPROJ 2096

typedef __attribute__((ext_vector_type(8))) short short8;
typedef __attribute__((ext_vector_type(4))) float f32x4;
typedef __hip_bfloat16 bf16;
typedef unsigned int u32;

__device__ __forceinline__ u32 fbits(float f) { return __float_as_uint(f); }
__device__ __forceinline__ float ubits(u32 u) { return __uint_as_float(u); }
// pack two fp32 into one u32 of bf16 (truncation): low16 = a, high16 = b
__device__ __forceinline__ u32 pack_bf(float a, float b) {
  return (fbits(b) & 0xffff0000u) | (fbits(a) >> 16);
}

// ---------------- block-wide sum reduction (256 threads = 4 waves) ----------
__device__ __forceinline__ float block_sum(float v, float* sbuf) {
#pragma unroll
  for (int o = 32; o > 0; o >>= 1) v += __shfl_down(v, o, 64);
  int lane = threadIdx.x & 63, wid = threadIdx.x >> 6;
  if (lane == 0) sbuf[wid] = v;
  __syncthreads();
  if (threadIdx.x == 0) {
    float t = 0.f;
    for (int i = 0; i < 4; i++) t += sbuf[i];
    sbuf[0] = t;
  }
  __syncthreads();
  return sbuf[0];
}

// ---------------- LayerNorm over 512, bf16 out ------------------------------
__global__ __launch_bounds__(256) void ln512_bf16_kernel(
    const float* __restrict__ x, const float* __restrict__ w,
    const float* __restrict__ b, bf16* __restrict__ out) {
  __shared__ float s1[8], s2[8];
  int row = blockIdx.x;
  const float* xr = x + (size_t)row * D_MODEL;
  bf16* outr = out + (size_t)row * D_MODEL;
  int c0 = threadIdx.x, c1 = threadIdx.x + 256;
  float v0 = xr[c0], v1 = xr[c1];
  float s  = block_sum(v0 + v1, s1);
  float ss = block_sum(v0 * v0 + v1 * v1, s2);
  float mean = s * (1.f / 512.f);
  float var  = ss * (1.f / 512.f) - mean * mean;
  float inv  = rsqrtf(var + 1e-5f);
  outr[c0] = __float2bfloat16((v0 - mean) * inv * w[c0] + b[c0]);
  outr[c1] = __float2bfloat16((v1 - mean) * inv * w[c1] + b[c1]);
}

// ---------------- weight convert + transpose: fp32 [K][N] -> bf16 [Npad][K] -
__global__ __launch_bounds__(256) void wconv_t_kernel(
    const float* __restrict__ w, bf16* __restrict__ wt,
    int K, int N, int Npad) {
  __shared__ float tile[32][33];
  int n0 = blockIdx.x * 32, k0 = blockIdx.y * 32;
  int tx = threadIdx.x & 31, ty = threadIdx.x >> 5;  // 32 x 8
#pragma unroll
  for (int i = 0; i < 4; i++) {
    int k = k0 + ty + i * 8, n = n0 + tx;
    tile[ty + i * 8][tx] = (k < K && n < N) ? w[(size_t)k * N + n] : 0.f;
  }
  __syncthreads();
#pragma unroll
  for (int i = 0; i < 4; i++) {
    int n = n0 + ty + i * 8, k = k0 + tx;
    if (n < Npad && k < K) wt[(size_t)n * K + k] = __float2bfloat16(tile[tx][ty + i * 8]);
  }
}

// ---------------- fp32-out MFMA GEMM, 2-phase double-buffered ---------------
template<int BM, int BN, int WN, int MR, int NR>
__global__ __launch_bounds__(256) void mfma_gemm_kernel(
    const bf16* __restrict__ A, const bf16* __restrict__ Bt,
    const float* __restrict__ bias, int nbias,
    const float* __restrict__ resid,
    float* __restrict__ C, int ldc, int K) {
  constexpr int ROWS = BM + BN;
  constexpr int ISS  = ROWS / 64;
  __shared__ __align__(16) bf16 sAB[2][ROWS][32];

  int wid = threadIdx.x >> 6, lane = threadIdx.x & 63;
  int row0 = blockIdx.y * BM, col0 = blockIdx.x * BN;
  int wr = (wid / WN) * (MR * 16);
  int wc = (wid % WN) * (NR * 16);
  int lr = lane >> 2;
  int lc = (lane & 3) * 8;

  f32x4 acc[MR][NR];
#pragma unroll
  for (int m = 0; m < MR; m++)
#pragma unroll
    for (int n = 0; n < NR; n++) acc[m][n] = (f32x4){0.f, 0.f, 0.f, 0.f};

  auto stage = [&](int buf, int k0) {
#pragma unroll
    for (int i = 0; i < ISS; i++) {
      int rb = (wid * ISS + i) * 16;
      int r = rb + lr;
      const bf16* src = (r < BM)
          ? A  + (size_t)(row0 + r) * K + k0 + lc
          : Bt + (size_t)(col0 + (r - BM)) * K + k0 + lc;
      __builtin_amdgcn_global_load_lds(
          (const __attribute__((address_space(1))) void*)src,
          (__attribute__((address_space(3))) void*)&sAB[buf][rb][0], 16, 0, 0);
    }
  };

  stage(0, 0);
  asm volatile("s_waitcnt vmcnt(0)" ::: "memory");
  __syncthreads();

  int cur = 0;
  for (int k0 = 0; k0 < K; k0 += 32, cur ^= 1) {
    if (k0 + 32 < K) stage(cur ^ 1, k0 + 32);
    short8 a[MR], b[NR];
    int kk = (lane >> 4) * 8;
#pragma unroll
    for (int m = 0; m < MR; m++)
      a[m] = *(const short8*)&sAB[cur][wr + m * 16 + (lane & 15)][kk];
#pragma unroll
    for (int n = 0; n < NR; n++)
      b[n] = *(const short8*)&sAB[cur][BM + wc + n * 16 + (lane & 15)][kk];
#pragma unroll
    for (int m = 0; m < MR; m++)
#pragma unroll
      for (int n = 0; n < NR; n++)
        acc[m][n] = __builtin_amdgcn_mfma_f32_16x16x32_bf16(a[m], b[n], acc[m][n], 0, 0, 0);
    asm volatile("s_waitcnt vmcnt(0)" ::: "memory");
    __syncthreads();
  }

  int crow = row0 + wr + (lane >> 4) * 4;
  int ccol = col0 + wc + (lane & 15);
#pragma unroll
  for (int m = 0; m < MR; m++) {
#pragma unroll
    for (int n = 0; n < NR; n++) {
      int colg = ccol + n * 16;
      float bv = bias ? ((colg < nbias) ? bias[colg] : 0.f) : 0.f;
#pragma unroll
      for (int j = 0; j < 4; j++) {
        int rowg = crow + m * 16 + j;
        float v = acc[m][n][j] + bv;
        if (resid) v += resid[(size_t)rowg * ldc + colg];
        C[(size_t)rowg * ldc + colg] = v;
      }
    }
  }
}

// ---------------- in-proj GEMM (2-phase): bf16 out + fp32 aux ---------------
__global__ __launch_bounds__(256) void inproj_gemm_kernel(
    const bf16* __restrict__ A, const bf16* __restrict__ Bt,
    const float* __restrict__ bias,
    bf16* __restrict__ Cb, float* __restrict__ aux, int K) {
  constexpr int BM = 128, ROWS = 256, ISS = 4;
  __shared__ __align__(16) bf16 sAB[2][ROWS][32];

  int wid = threadIdx.x >> 6, lane = threadIdx.x & 63;
  int row0 = blockIdx.y * BM, col0 = blockIdx.x * 128;
  int wr = (wid >> 1) * 64;
  int wc = (wid & 1) * 64;
  int lr = lane >> 2;
  int lc = (lane & 3) * 8;

  f32x4 acc[4][4];
#pragma unroll
  for (int m = 0; m < 4; m++)
#pragma unroll
    for (int n = 0; n < 4; n++) acc[m][n] = (f32x4){0.f, 0.f, 0.f, 0.f};

  auto stage = [&](int buf, int k0) {
#pragma unroll
    for (int i = 0; i < ISS; i++) {
      int rb = (wid * ISS + i) * 16;
      int r = rb + lr;
      const bf16* src = (r < BM)
          ? A  + (size_t)(row0 + r) * K + k0 + lc
          : Bt + (size_t)(col0 + (r - BM)) * K + k0 + lc;
      __builtin_amdgcn_global_load_lds(
          (const __attribute__((address_space(1))) void*)src,
          (__attribute__((address_space(3))) void*)&sAB[buf][rb][0], 16, 0, 0);
    }
  };

  stage(0, 0);
  asm volatile("s_waitcnt vmcnt(0)" ::: "memory");
  __syncthreads();

  int cur = 0;
  for (int k0 = 0; k0 < K; k0 += 32, cur ^= 1) {
    if (k0 + 32 < K) stage(cur ^ 1, k0 + 32);
    short8 a[4], b[4];
    int kk = (lane >> 4) * 8;
#pragma unroll
    for (int m = 0; m < 4; m++)
      a[m] = *(const short8*)&sAB[cur][wr + m * 16 + (lane & 15)][kk];
#pragma unroll
    for (int n = 0; n < 4; n++)
      b[n] = *(const short8*)&sAB[cur][BM + wc + n * 16 + (lane & 15)][kk];
#pragma unroll
    for (int m = 0; m < 4; m++)
#pragma unroll
      for (int n = 0; n < 4; n++)
        acc[m][n] = __builtin_amdgcn_mfma_f32_16x16x32_bf16(a[m], b[n], acc[m][n], 0, 0, 0);
    asm volatile("s_waitcnt vmcnt(0)" ::: "memory");
    __syncthreads();
  }

  int crow = row0 + wr + (lane >> 4) * 4;
  int ccol = col0 + wc + (lane & 15);
#pragma unroll
  for (int m = 0; m < 4; m++) {
#pragma unroll
    for (int n = 0; n < 4; n++) {
      int colg = ccol + n * 16;
      float bv = (colg < NPROJ) ? bias[colg] : 0.f;
#pragma unroll
      for (int j = 0; j < 4; j++) {
        int rowg = crow + m * 16 + j;
        float v = acc[m][n][j] + bv;
        Cb[(size_t)rowg * PROJ_LD + colg] = __float2bfloat16(v);
        if (colg >= 2048 && colg < 2112)
          aux[(size_t)rowg * 64 + (colg - 2048)] = v;
      }
    }
  }
}

// ---------------- FF1 GEMM fused with SiLU gate (2-phase) -> bf16 -----------
__global__ __launch_bounds__(256) void ff1_fused_kernel(
    const bf16* __restrict__ A, const bf16* __restrict__ Bt,
    const float* __restrict__ bias, bf16* __restrict__ out, int K) {
  constexpr int BM = 128, ROWS = 384, ISS = 6;
  __shared__ __align__(16) bf16 sAB[2][ROWS][32];

  int wid = threadIdx.x >> 6, lane = threadIdx.x & 63;
  int row0 = blockIdx.y * BM, col0 = blockIdx.x * 128;
  int wr = (wid >> 1) * 64;
  int wc = (wid & 1) * 64;
  int lr = lane >> 2;
  int lc = (lane & 3) * 8;

  f32x4 acc1[4][4], acc2[4][4];
#pragma unroll
  for (int m = 0; m < 4; m++)
#pragma unroll
    for (int n = 0; n < 4; n++) {
      acc1[m][n] = (f32x4){0.f, 0.f, 0.f, 0.f};
      acc2[m][n] = (f32x4){0.f, 0.f, 0.f, 0.f};
    }

  auto stage = [&](int buf, int k0) {
#pragma unroll
    for (int i = 0; i < ISS; i++) {
      int rb = (wid * ISS + i) * 16;
      int r = rb + lr;
      const bf16* src;
      if (r < BM)       src = A  + (size_t)(row0 + r) * K + k0 + lc;
      else if (r < 256) src = Bt + (size_t)(col0 + (r - 128)) * K + k0 + lc;
      else              src = Bt + (size_t)(1024 + col0 + (r - 256)) * K + k0 + lc;
      __builtin_amdgcn_global_load_lds(
          (const __attribute__((address_space(1))) void*)src,
          (__attribute__((address_space(3))) void*)&sAB[buf][rb][0], 16, 0, 0);
    }
  };

  stage(0, 0);
  asm volatile("s_waitcnt vmcnt(0)" ::: "memory");
  __syncthreads();

  int cur = 0;
  for (int k0 = 0; k0 < K; k0 += 32, cur ^= 1) {
    if (k0 + 32 < K) stage(cur ^ 1, k0 + 32);
    short8 a[4], b1[4], b2[4];
    int kk = (lane >> 4) * 8;
#pragma unroll
    for (int m = 0; m < 4; m++)
      a[m] = *(const short8*)&sAB[cur][wr + m * 16 + (lane & 15)][kk];
#pragma unroll
    for (int n = 0; n < 4; n++) {
      b1[n] = *(const short8*)&sAB[cur][128 + wc + n * 16 + (lane & 15)][kk];
      b2[n] = *(const short8*)&sAB[cur][256 + wc + n * 16 + (lane & 15)][kk];
    }
#pragma unroll
    for (int m = 0; m < 4; m++)
#pragma unroll
      for (int n = 0; n < 4; n++) {
        acc1[m][n] = __builtin_amdgcn_mfma_f32_16x16x32_bf16(a[m], b1[n], acc1[m][n], 0, 0, 0);
        acc2[m][n] = __builtin_amdgcn_mfma_f32_16x16x32_bf16(a[m], b2[n], acc2[m][n], 0, 0, 0);
      }
    asm volatile("s_waitcnt vmcnt(0)" ::: "memory");
    __syncthreads();
  }

  int crow = row0 + wr + (lane >> 4) * 4;
  int ccol = col0 + wc + (lane & 15);
#pragma unroll
  for (int m = 0; m < 4; m++) {
#pragma unroll
    for (int n = 0; n < 4; n++) {
      int colg = ccol + n * 16;
      float bv1 = bias[colg];
      float bv2 = bias[1024 + colg];
#pragma unroll
      for (int j = 0; j < 4; j++) {
        int rowg = crow + m * 16 + j;
        float f1 = acc1[m][n][j] + bv1;
        float g  = acc2[m][n][j] + bv2;
        float sg = g / (1.f + expf(-g));
        out[(size_t)rowg * 1024 + colg] = __float2bfloat16(f1 * sg);
      }
    }
  }
}

// ---------------- tree scan: n-split (8 states/thread), 1024 blocks ---------
// block = (b, h, ps, nh); lane = (w, q): w = lane>>2, pl = wid*4 + q.
// Each thread: states n in [nh*8, nh*8+8), packed-bf16 transport (4 bpermute).
// Partial y (sum over its 8 n's) -> y0/y1; gate_rms adds the halves.
__global__ __launch_bounds__(256) void tree_scan_kernel(
    const bf16* __restrict__ xb, const float* __restrict__ aux,
    const int* __restrict__ parent,
    const float* __restrict__ A_log, const float* __restrict__ dt_bias,
    const float* __restrict__ Dp, bf16* __restrict__ y0,
    bf16* __restrict__ y1) {
  const int tid = threadIdx.x;
  const int nh = blockIdx.x & 1;
  const int ps = (blockIdx.x >> 1) & 3;
  const int h  = (blockIdx.x >> 3) & 15;
  const int b  = blockIdx.x >> 7;
  const int wid = tid >> 6;
  const int lane = tid & 63;
  const int w = lane >> 2;
  const int q = lane & 3;
  const int pl = wid * 4 + q;

  // BCs[t][w]: words [0:4)=B-half (bf16 pairs), [4:8)=C-half; stride 12 (48B)
  __shared__ __align__(16) u32   BCs[8][16][12];
  __shared__ __align__(16) float dAs[16][8];
  __shared__ __align__(16) float dtss[16][8];
  __shared__ __align__(16) int   pars[16][8];

  const float Ah  = -expf(A_log[h]);
  const float dtb = dt_bias[h];
  const float Dh  = nh ? 0.f : Dp[h];
  const int xcol = 1024 + (h << 6) + (ps << 4) + pl;
  const int ycol = (h << 6) + (ps << 4) + pl;
  bf16* __restrict__ yout = nh ? y1 : y0;

  float hst[8];
#pragma unroll
  for (int n = 0; n < 8; n++) hst[n] = 0.f;

  // staging map: tid = t*32 + w*2 + half
  const int sg_t = tid >> 5, sg_w = (tid >> 1) & 15, sg_h = tid & 1;

  for (int c = 0; c < 8; c++) {
    const int t0 = c * 8;
    __syncthreads();  // previous chunk's compute done
    // x prefetch: 8 bf16 global loads for this lane's (w, pl)
    float xv[8];
#pragma unroll
    for (int tt = 0; tt < 8; tt++) {
      size_t row = ((size_t)(b * NT + t0 + tt)) * NW + w;
      xv[tt] = __bfloat162float(xb[row * PROJ_LD + xcol]);
    }
    // stage dt / dA / parent
    if (tid < 128) {
      int t = tid >> 4, wv = tid & 15;
      size_t row = ((size_t)(b * NT + t0 + t)) * NW + wv;
      float dtr = aux[row * 64 + 32 + h] + dtb;
      float dtv = (dtr > 20.f) ? dtr : log1pf(expf(dtr));
      dtss[wv][t] = dtv;
      dAs[wv][t]  = expf(dtv * Ah);
      pars[wv][t] = parent[row];
    }
    // stage B-half or C-half (8 floats -> 4 packed words) per (t,w,half)
    {
      size_t row = ((size_t)(b * NT + t0 + sg_t)) * NW + sg_w;
      const float* src = aux + row * 64 + sg_h * 16 + nh * 8;
      float4 v0 = *(const float4*)&src[0];
      float4 v1 = *(const float4*)&src[4];
      uint4 p = {pack_bf(v0.x, v0.y), pack_bf(v0.z, v0.w),
                 pack_bf(v1.x, v1.y), pack_bf(v1.z, v1.w)};
      *(uint4*)&BCs[sg_t][sg_w][sg_h * 4] = p;
    }
    __syncthreads();
    // reg-pack per-lane (w) params
    float dAr[8], dtr8[8];
    int parr[8];
    *(float4*)&dAr[0]  = *(const float4*)&dAs[w][0];
    *(float4*)&dAr[4]  = *(const float4*)&dAs[w][4];
    *(float4*)&dtr8[0] = *(const float4*)&dtss[w][0];
    *(float4*)&dtr8[4] = *(const float4*)&dtss[w][4];
    *(int4*)&parr[0]   = *(const int4*)&pars[w][0];
    *(int4*)&parr[4]   = *(const int4*)&pars[w][4];

#pragma unroll
    for (int tt = 0; tt < 8; tt++) {
      float dA  = dAr[tt];
      float dtx = dtr8[tt] * xv[tt];
      int   par = parr[tt];
      int gidx = (((par << 2) | q) << 2);
      // pack 4 state pairs to bf16, gather via 4 bpermutes
      u32 pk[4];
#pragma unroll
      for (int i = 0; i < 4; i++)
        pk[i] = (u32)__builtin_amdgcn_ds_bpermute(
            gidx, (int)pack_bf(hst[2 * i], hst[2 * i + 1]));
      // B/C packed rows (broadcast within quad)
      uint4 bu4 = *(const uint4*)&BCs[tt][w][0];
      uint4 cu4 = *(const uint4*)&BCs[tt][w][4];
      u32 bwv[4] = {bu4.x, bu4.y, bu4.z, bu4.w};
      u32 cwv[4] = {cu4.x, cu4.y, cu4.z, cu4.w};
      float yv = 0.f;
#pragma unroll
      for (int i = 0; i < 4; i++) {
        u32 g = pk[i], bu = bwv[i], cu = cwv[i];
        float hp0 = ubits(g << 16),  hp1 = ubits(g & 0xffff0000u);
        float bl  = ubits(bu << 16), bh  = ubits(bu & 0xffff0000u);
        float cl  = ubits(cu << 16), ch  = ubits(cu & 0xffff0000u);
        float h0 = fmaf(dA, hp0, dtx * bl);
        float h1 = fmaf(dA, hp1, dtx * bh);
        hst[2 * i] = h0;
        hst[2 * i + 1] = h1;
        yv = fmaf(h0, cl, fmaf(h1, ch, yv));
      }
      size_t row = ((size_t)(b * NT + t0 + tt)) * NW + w;
      yout[row * D_INNER + ycol] = __float2bfloat16(fmaf(Dh, xv[tt], yv));
    }
  }
}

// ---------------- gated RMSNorm (bf16 in ×2 halves, bf16 out) ---------------
__global__ __launch_bounds__(256) void gate_rms_kernel(
    const bf16* __restrict__ y0, const bf16* __restrict__ y1,
    const bf16* __restrict__ projb,
    const float* __restrict__ norm_w, bf16* __restrict__ out) {
  __shared__ float sbuf[8];
  int row = blockIdx.x;
  const bf16* yr0 = y0 + (size_t)row * D_INNER;
  const bf16* yr1 = y1 + (size_t)row * D_INNER;
  const bf16* zr = projb + (size_t)row * PROJ_LD;  // z = cols [0,1024)
  int c = threadIdx.x * 4;
  bf16 a4[4], b4[4], z4[4];
  *(uint2*)a4 = *(const uint2*)&yr0[c];
  *(uint2*)b4 = *(const uint2*)&yr1[c];
  *(uint2*)z4 = *(const uint2*)&zr[c];
  float gv[4];
  float ss = 0.f;
#pragma unroll
  for (int j = 0; j < 4; j++) {
    float z = __bfloat162float(z4[j]);
    float yv = __bfloat162float(a4[j]) + __bfloat162float(b4[j]);
    float t = yv * (z / (1.f + expf(-z)));
    gv[j] = t;
    ss += t * t;
  }
  ss = block_sum(ss, sbuf);
  float scale = rsqrtf(ss * (1.f / 1024.f) + 1e-5f);
  bf16 o4[4];
#pragma unroll
  for (int j = 0; j < 4; j++) o4[j] = __float2bfloat16(gv[j] * scale * norm_w[c + j]);
  *(uint2*)&out[(size_t)row * D_INNER + c] = *(uint2*)o4;
}

extern "C" void kernel_launch(void* const* d_in, const int* in_sizes, int n_in,
                              void* d_out, int out_size, void* d_ws, size_t ws_size,
                              hipStream_t stream) {
  const float* x       = (const float*)d_in[0];
  const int*   parent  = (const int*)d_in[1];
  const float* ln1_w   = (const float*)d_in[2];
  const float* ln1_b   = (const float*)d_in[3];
  const float* in_w    = (const float*)d_in[4];
  const float* in_b    = (const float*)d_in[5];
  const float* A_log   = (const float*)d_in[6];
  const float* dt_bias = (const float*)d_in[7];
  const float* Dp      = (const float*)d_in[8];
  const float* norm_w  = (const float*)d_in[9];
  const float* out_w   = (const float*)d_in[10];
  const float* out_b   = (const float*)d_in[11];
  const float* ln2_w   = (const float*)d_in[12];
  const float* ln2_b   = (const float*)d_in[13];
  const float* ff1_w   = (const float*)d_in[14];
  const float* ff1_b   = (const float*)d_in[15];
  const float* ff2_w   = (const float*)d_in[16];
  const float* ff2_b   = (const float*)d_in[17];
  float* outp = (float*)d_out;

  char* wp = (char*)d_ws;
  bf16* xnb    = (bf16*)wp;  wp += (size_t)MROWS * D_MODEL * 2;
  bf16* in_wt  = (bf16*)wp;  wp += (size_t)PROJ_LD * D_MODEL * 2;
  bf16* out_wt = (bf16*)wp;  wp += (size_t)D_MODEL * D_INNER * 2;
  bf16* ff1_wt = (bf16*)wp;  wp += (size_t)2048 * D_MODEL * 2;
  bf16* ff2_wt = (bf16*)wp;  wp += (size_t)D_MODEL * D_INNER * 2;
  bf16* projb  = (bf16*)wp;  wp += (size_t)MROWS * PROJ_LD * 2;
  float* aux   = (float*)wp; wp += (size_t)MROWS * 64 * 4;
  bf16* yb0    = (bf16*)wp;  wp += (size_t)MROWS * D_INNER * 2;
  bf16* yb1    = (bf16*)wp;  wp += (size_t)MROWS * D_INNER * 2;
  bf16* ygb    = (bf16*)wp;  wp += (size_t)MROWS * D_INNER * 2;
  float* xmid  = outp;  // d_out doubles as xmid

  dim3 blk(256);
  wconv_t_kernel<<<dim3(PROJ_LD / 32, D_MODEL / 32), blk, 0, stream>>>(
      in_w, in_wt, D_MODEL, NPROJ, PROJ_LD);
  wconv_t_kernel<<<dim3(D_MODEL / 32, D_INNER / 32), blk, 0, stream>>>(
      out_w, out_wt, D_INNER, D_MODEL, D_MODEL);
  wconv_t_kernel<<<dim3(2048 / 32, D_MODEL / 32), blk, 0, stream>>>(
      ff1_w, ff1_wt, D_MODEL, 2048, 2048);
  wconv_t_kernel<<<dim3(D_MODEL / 32, D_INNER / 32), blk, 0, stream>>>(
      ff2_w, ff2_wt, D_INNER, D_MODEL, D_MODEL);

  // 1) LN1 -> bf16
  ln512_bf16_kernel<<<MROWS, blk, 0, stream>>>(x, ln1_w, ln1_b, xnb);
  // 2) in-proj GEMM -> projb (bf16) + aux (fp32 B/C/dt)
  inproj_gemm_kernel<<<dim3(PROJ_LD / 128, MROWS / 128), blk, 0, stream>>>(
      xnb, in_wt, in_b, projb, aux, D_MODEL);
  // 3) tree scan (n-split) -> yb0 + yb1 (bf16 partials)
  tree_scan_kernel<<<NB * NHEAD * 4 * 2, blk, 0, stream>>>(
      projb, aux, parent, A_log, dt_bias, Dp, yb0, yb1);
  // 4) gated RMSNorm (sums halves) -> ygb (bf16)
  gate_rms_kernel<<<MROWS, blk, 0, stream>>>(yb0, yb1, projb, norm_w, ygb);
  // 5) out-proj GEMM + resid(x) -> xmid (fp32)
  mfma_gemm_kernel<64, 128, 4, 4, 2><<<dim3(D_MODEL / 128, MROWS / 64), blk, 0, stream>>>(
      ygb, out_wt, out_b, D_MODEL, x, xmid, D_MODEL, D_INNER);
  // 6) LN2 -> xnb
  ln512_bf16_kernel<<<MROWS, blk, 0, stream>>>(xmid, ln2_w, ln2_b, xnb);
  // 7) FF1 GEMM + SiLU gate fused -> ygb (bf16, reuse)
  ff1_fused_kernel<<<dim3(8, MROWS / 128), blk, 0, stream>>>(
      xnb, ff1_wt, ff1_b, ygb, D_MODEL);
  // 8) FF2 GEMM + resid(xmid) -> d_out
  mfma_gemm_kernel<64, 128, 4, 4, 2><<<dim3(D_MODEL / 128, MROWS / 64), blk, 0, stream>>>(
      ygb, ff2_wt, ff2_b, D_MODEL, xmid, outp, D_MODEL, D_INNER);
}

// Round 8
// 217.687 us; speedup vs baseline: 1.0273x; 1.0273x over previous
//
#include <hip/hip_runtime.h>
#include <hip/hip_bf16.h>
#include <cmath>

#define D_MODEL 512
#define D_INNER 1024
#define NHEAD 16
#define HDIM 64
#define NSTATE 16
#define NB 8
#define NT 64
#define NW 16
#define MROWS 8192      // NB*NT*NW
#define PROJ_LD 2176    // padded 2096 -> 17*128
#define NPROJ 2096

typedef __attribute__((ext_vector_type(8))) short short8;
typedef __attribute__((ext_vector_type(4))) float f32x4;
typedef __hip_bfloat16 bf16;
typedef unsigned int u32;

__device__ __forceinline__ u32 fbits(float f) { return __float_as_uint(f); }
__device__ __forceinline__ float ubits(u32 u) { return __uint_as_float(u); }
__device__ __forceinline__ u32 pack_bf(float a, float b) {
  return (fbits(b) & 0xffff0000u) | (fbits(a) >> 16);
}

// ---------------- block-wide sum reduction (256 threads = 4 waves) ----------
__device__ __forceinline__ float block_sum(float v, float* sbuf) {
#pragma unroll
  for (int o = 32; o > 0; o >>= 1) v += __shfl_down(v, o, 64);
  int lane = threadIdx.x & 63, wid = threadIdx.x >> 6;
  if (lane == 0) sbuf[wid] = v;
  __syncthreads();
  if (threadIdx.x == 0) {
    float t = 0.f;
    for (int i = 0; i < 4; i++) t += sbuf[i];
    sbuf[0] = t;
  }
  __syncthreads();
  return sbuf[0];
}

// ---------------- LayerNorm over 512, bf16 out (LN1) ------------------------
__global__ __launch_bounds__(256) void ln512_bf16_kernel(
    const float* __restrict__ x, const float* __restrict__ w,
    const float* __restrict__ b, bf16* __restrict__ out) {
  __shared__ float s1[8], s2[8];
  int row = blockIdx.x;
  const float* xr = x + (size_t)row * D_MODEL;
  bf16* outr = out + (size_t)row * D_MODEL;
  int c0 = threadIdx.x, c1 = threadIdx.x + 256;
  float v0 = xr[c0], v1 = xr[c1];
  float s  = block_sum(v0 + v1, s1);
  float ss = block_sum(v0 * v0 + v1 * v1, s2);
  float mean = s * (1.f / 512.f);
  float var  = ss * (1.f / 512.f) - mean * mean;
  float inv  = rsqrtf(var + 1e-5f);
  outr[c0] = __float2bfloat16((v0 - mean) * inv * w[c0] + b[c0]);
  outr[c1] = __float2bfloat16((v1 - mean) * inv * w[c1] + b[c1]);
}

// ---------------- merged weight convert+transpose (4 configs in 1 grid) -----
// wt[n][k] = bf16(w[k][n] * (scale ? scale[k] : 1))
__global__ __launch_bounds__(256) void wconv_all_kernel(
    const float* __restrict__ in_w, bf16* __restrict__ in_wt,
    const float* __restrict__ out_w, bf16* __restrict__ out_wt,
    const float* __restrict__ norm_w,
    const float* __restrict__ ff1_w, bf16* __restrict__ ff1_wt,
    const float* __restrict__ ff2_w, bf16* __restrict__ ff2_wt) {
  __shared__ float tile[32][33];
  int id = blockIdx.x;
  const float* w; bf16* wt; const float* sc = nullptr;
  int K, N, Npad, bx, by;
  if (id < 1088)      { w = in_w;  wt = in_wt;  K = 512;  N = NPROJ; Npad = PROJ_LD; bx = id % 68;  by = id / 68; }
  else if (id < 1600) { int j = id - 1088; w = out_w; wt = out_wt; sc = norm_w; K = 1024; N = 512;  Npad = 512;  bx = j % 16; by = j / 16; }
  else if (id < 2624) { int j = id - 1600; w = ff1_w; wt = ff1_wt; K = 512;  N = 2048; Npad = 2048; bx = j % 64; by = j / 64; }
  else                { int j = id - 2624; w = ff2_w; wt = ff2_wt; K = 1024; N = 512;  Npad = 512;  bx = j % 16; by = j / 16; }
  int n0 = bx * 32, k0 = by * 32;
  int tx = threadIdx.x & 31, ty = threadIdx.x >> 5;  // 32 x 8
#pragma unroll
  for (int i = 0; i < 4; i++) {
    int k = k0 + ty + i * 8, n = n0 + tx;
    tile[ty + i * 8][tx] = (k < K && n < N) ? w[(size_t)k * N + n] : 0.f;
  }
  __syncthreads();
  float s = sc ? sc[k0 + tx] : 1.f;
#pragma unroll
  for (int i = 0; i < 4; i++) {
    int n = n0 + ty + i * 8, k = k0 + tx;
    if (n < Npad && k < K)
      wt[(size_t)n * K + k] = __float2bfloat16(tile[tx][ty + i * 8] * s);
  }
}

// ---------------- fp32-out MFMA GEMM, 2-phase double-buffered (ff2) ---------
template<int BM, int BN, int WN, int MR, int NR>
__global__ __launch_bounds__(256) void mfma_gemm_kernel(
    const bf16* __restrict__ A, const bf16* __restrict__ Bt,
    const float* __restrict__ bias, int nbias,
    const float* __restrict__ resid,
    float* __restrict__ C, int ldc, int K) {
  constexpr int ROWS = BM + BN;
  constexpr int ISS  = ROWS / 64;
  __shared__ __align__(16) bf16 sAB[2][ROWS][32];

  int wid = threadIdx.x >> 6, lane = threadIdx.x & 63;
  int row0 = blockIdx.y * BM, col0 = blockIdx.x * BN;
  int wr = (wid / WN) * (MR * 16);
  int wc = (wid % WN) * (NR * 16);
  int lr = lane >> 2;
  int lc = (lane & 3) * 8;

  f32x4 acc[MR][NR];
#pragma unroll
  for (int m = 0; m < MR; m++)
#pragma unroll
    for (int n = 0; n < NR; n++) acc[m][n] = (f32x4){0.f, 0.f, 0.f, 0.f};

  auto stage = [&](int buf, int k0) {
#pragma unroll
    for (int i = 0; i < ISS; i++) {
      int rb = (wid * ISS + i) * 16;
      int r = rb + lr;
      const bf16* src = (r < BM)
          ? A  + (size_t)(row0 + r) * K + k0 + lc
          : Bt + (size_t)(col0 + (r - BM)) * K + k0 + lc;
      __builtin_amdgcn_global_load_lds(
          (const __attribute__((address_space(1))) void*)src,
          (__attribute__((address_space(3))) void*)&sAB[buf][rb][0], 16, 0, 0);
    }
  };

  stage(0, 0);
  asm volatile("s_waitcnt vmcnt(0)" ::: "memory");
  __syncthreads();

  int cur = 0;
  for (int k0 = 0; k0 < K; k0 += 32, cur ^= 1) {
    if (k0 + 32 < K) stage(cur ^ 1, k0 + 32);
    short8 a[MR], b[NR];
    int kk = (lane >> 4) * 8;
#pragma unroll
    for (int m = 0; m < MR; m++)
      a[m] = *(const short8*)&sAB[cur][wr + m * 16 + (lane & 15)][kk];
#pragma unroll
    for (int n = 0; n < NR; n++)
      b[n] = *(const short8*)&sAB[cur][BM + wc + n * 16 + (lane & 15)][kk];
#pragma unroll
    for (int m = 0; m < MR; m++)
#pragma unroll
      for (int n = 0; n < NR; n++)
        acc[m][n] = __builtin_amdgcn_mfma_f32_16x16x32_bf16(a[m], b[n], acc[m][n], 0, 0, 0);
    asm volatile("s_waitcnt vmcnt(0)" ::: "memory");
    __syncthreads();
  }

  int crow = row0 + wr + (lane >> 4) * 4;
  int ccol = col0 + wc + (lane & 15);
#pragma unroll
  for (int m = 0; m < MR; m++) {
#pragma unroll
    for (int n = 0; n < NR; n++) {
      int colg = ccol + n * 16;
      float bv = bias ? ((colg < nbias) ? bias[colg] : 0.f) : 0.f;
#pragma unroll
      for (int j = 0; j < 4; j++) {
        int rowg = crow + m * 16 + j;
        float v = acc[m][n][j] + bv;
        if (resid) v += resid[(size_t)rowg * ldc + colg];
        C[(size_t)rowg * ldc + colg] = v;
      }
    }
  }
}

// ---------------- in-proj GEMM (2-phase): bf16 out + fp32 aux ---------------
__global__ __launch_bounds__(256) void inproj_gemm_kernel(
    const bf16* __restrict__ A, const bf16* __restrict__ Bt,
    const float* __restrict__ bias,
    bf16* __restrict__ Cb, float* __restrict__ aux, int K) {
  constexpr int BM = 128, ROWS = 256, ISS = 4;
  __shared__ __align__(16) bf16 sAB[2][ROWS][32];

  int wid = threadIdx.x >> 6, lane = threadIdx.x & 63;
  int row0 = blockIdx.y * BM, col0 = blockIdx.x * 128;
  int wr = (wid >> 1) * 64;
  int wc = (wid & 1) * 64;
  int lr = lane >> 2;
  int lc = (lane & 3) * 8;

  f32x4 acc[4][4];
#pragma unroll
  for (int m = 0; m < 4; m++)
#pragma unroll
    for (int n = 0; n < 4; n++) acc[m][n] = (f32x4){0.f, 0.f, 0.f, 0.f};

  auto stage = [&](int buf, int k0) {
#pragma unroll
    for (int i = 0; i < ISS; i++) {
      int rb = (wid * ISS + i) * 16;
      int r = rb + lr;
      const bf16* src = (r < BM)
          ? A  + (size_t)(row0 + r) * K + k0 + lc
          : Bt + (size_t)(col0 + (r - BM)) * K + k0 + lc;
      __builtin_amdgcn_global_load_lds(
          (const __attribute__((address_space(1))) void*)src,
          (__attribute__((address_space(3))) void*)&sAB[buf][rb][0], 16, 0, 0);
    }
  };

  stage(0, 0);
  asm volatile("s_waitcnt vmcnt(0)" ::: "memory");
  __syncthreads();

  int cur = 0;
  for (int k0 = 0; k0 < K; k0 += 32, cur ^= 1) {
    if (k0 + 32 < K) stage(cur ^ 1, k0 + 32);
    short8 a[4], b[4];
    int kk = (lane >> 4) * 8;
#pragma unroll
    for (int m = 0; m < 4; m++)
      a[m] = *(const short8*)&sAB[cur][wr + m * 16 + (lane & 15)][kk];
#pragma unroll
    for (int n = 0; n < 4; n++)
      b[n] = *(const short8*)&sAB[cur][BM + wc + n * 16 + (lane & 15)][kk];
#pragma unroll
    for (int m = 0; m < 4; m++)
#pragma unroll
      for (int n = 0; n < 4; n++)
        acc[m][n] = __builtin_amdgcn_mfma_f32_16x16x32_bf16(a[m], b[n], acc[m][n], 0, 0, 0);
    asm volatile("s_waitcnt vmcnt(0)" ::: "memory");
    __syncthreads();
  }

  int crow = row0 + wr + (lane >> 4) * 4;
  int ccol = col0 + wc + (lane & 15);
#pragma unroll
  for (int m = 0; m < 4; m++) {
#pragma unroll
    for (int n = 0; n < 4; n++) {
      int colg = ccol + n * 16;
      float bv = (colg < NPROJ) ? bias[colg] : 0.f;
#pragma unroll
      for (int j = 0; j < 4; j++) {
        int rowg = crow + m * 16 + j;
        float v = acc[m][n][j] + bv;
        Cb[(size_t)rowg * PROJ_LD + colg] = __float2bfloat16(v);
        if (colg >= 2048 && colg < 2112)
          aux[(size_t)rowg * 64 + (colg - 2048)] = v;
      }
    }
  }
}

// ---------------- FF1 GEMM fused with SiLU gate (2-phase) -> bf16 -----------
__global__ __launch_bounds__(256) void ff1_fused_kernel(
    const bf16* __restrict__ A, const bf16* __restrict__ Bt,
    const float* __restrict__ bias, bf16* __restrict__ out, int K) {
  constexpr int BM = 128, ROWS = 384, ISS = 6;
  __shared__ __align__(16) bf16 sAB[2][ROWS][32];

  int wid = threadIdx.x >> 6, lane = threadIdx.x & 63;
  int row0 = blockIdx.y * BM, col0 = blockIdx.x * 128;
  int wr = (wid >> 1) * 64;
  int wc = (wid & 1) * 64;
  int lr = lane >> 2;
  int lc = (lane & 3) * 8;

  f32x4 acc1[4][4], acc2[4][4];
#pragma unroll
  for (int m = 0; m < 4; m++)
#pragma unroll
    for (int n = 0; n < 4; n++) {
      acc1[m][n] = (f32x4){0.f, 0.f, 0.f, 0.f};
      acc2[m][n] = (f32x4){0.f, 0.f, 0.f, 0.f};
    }

  auto stage = [&](int buf, int k0) {
#pragma unroll
    for (int i = 0; i < ISS; i++) {
      int rb = (wid * ISS + i) * 16;
      int r = rb + lr;
      const bf16* src;
      if (r < BM)       src = A  + (size_t)(row0 + r) * K + k0 + lc;
      else if (r < 256) src = Bt + (size_t)(col0 + (r - 128)) * K + k0 + lc;
      else              src = Bt + (size_t)(1024 + col0 + (r - 256)) * K + k0 + lc;
      __builtin_amdgcn_global_load_lds(
          (const __attribute__((address_space(1))) void*)src,
          (__attribute__((address_space(3))) void*)&sAB[buf][rb][0], 16, 0, 0);
    }
  };

  stage(0, 0);
  asm volatile("s_waitcnt vmcnt(0)" ::: "memory");
  __syncthreads();

  int cur = 0;
  for (int k0 = 0; k0 < K; k0 += 32, cur ^= 1) {
    if (k0 + 32 < K) stage(cur ^ 1, k0 + 32);
    short8 a[4], b1[4], b2[4];
    int kk = (lane >> 4) * 8;
#pragma unroll
    for (int m = 0; m < 4; m++)
      a[m] = *(const short8*)&sAB[cur][wr + m * 16 + (lane & 15)][kk];
#pragma unroll
    for (int n = 0; n < 4; n++) {
      b1[n] = *(const short8*)&sAB[cur][128 + wc + n * 16 + (lane & 15)][kk];
      b2[n] = *(const short8*)&sAB[cur][256 + wc + n * 16 + (lane & 15)][kk];
    }
#pragma unroll
    for (int m = 0; m < 4; m++)
#pragma unroll
      for (int n = 0; n < 4; n++) {
        acc1[m][n] = __builtin_amdgcn_mfma_f32_16x16x32_bf16(a[m], b1[n], acc1[m][n], 0, 0, 0);
        acc2[m][n] = __builtin_amdgcn_mfma_f32_16x16x32_bf16(a[m], b2[n], acc2[m][n], 0, 0, 0);
      }
    asm volatile("s_waitcnt vmcnt(0)" ::: "memory");
    __syncthreads();
  }

  int crow = row0 + wr + (lane >> 4) * 4;
  int ccol = col0 + wc + (lane & 15);
#pragma unroll
  for (int m = 0; m < 4; m++) {
#pragma unroll
    for (int n = 0; n < 4; n++) {
      int colg = ccol + n * 16;
      float bv1 = bias[colg];
      float bv2 = bias[1024 + colg];
#pragma unroll
      for (int j = 0; j < 4; j++) {
        int rowg = crow + m * 16 + j;
        float f1 = acc1[m][n][j] + bv1;
        float g  = acc2[m][n][j] + bv2;
        float sg = g / (1.f + expf(-g));
        out[(size_t)rowg * 1024 + colg] = __float2bfloat16(f1 * sg);
      }
    }
  }
}

// ---------------- fused: gate+RMS (folded) + out-proj + bias + resid + LN2 --
// BM=32, BN=512 (full row), grid = 256. norm_w pre-folded into Wt.
// rms scale applied per-row on the ACC (linearity); LN2 in-block (full row).
__global__ __launch_bounds__(256) void outproj_fused_kernel(
    const bf16* __restrict__ yb, const bf16* __restrict__ projb,
    const bf16* __restrict__ Wt, const float* __restrict__ out_b,
    const float* __restrict__ x, const float* __restrict__ ln2w,
    const float* __restrict__ ln2b,
    float* __restrict__ xmid, bf16* __restrict__ xnb) {
  constexpr int BM = 32, BN = 512, K = 1024;
  __shared__ __align__(16) bf16 Ab[2][BM][32];
  __shared__ __align__(16) bf16 Bb[2][BN][32];
  __shared__ float srow[BM];
  __shared__ float2 red[BM][4];

  const int tid = threadIdx.x, wid = tid >> 6, lane = tid & 63;
  const int row0 = blockIdx.x * BM;
  const int wc = wid * 128;
  const int lr = lane >> 2, lc4 = (lane & 3) * 8;
  const int ar = tid >> 3, akc = (tid & 7) * 4;

  f32x4 acc[2][8];
#pragma unroll
  for (int m = 0; m < 2; m++)
#pragma unroll
    for (int n = 0; n < 8; n++) acc[m][n] = (f32x4){0.f, 0.f, 0.f, 0.f};
  float ssp = 0.f;

  auto stageB = [&](int buf, int k0) {
#pragma unroll
    for (int i = 0; i < 8; i++) {
      int rb = (wid * 8 + i) * 16;
      const bf16* src = Wt + (size_t)(rb + lr) * K + k0 + lc4;
      __builtin_amdgcn_global_load_lds(
          (const __attribute__((address_space(1))) void*)src,
          (__attribute__((address_space(3))) void*)&Bb[buf][rb][0], 16, 0, 0);
    }
  };
  uint2 yv, zv;
  auto loadA = [&](int k0) {
    yv = *(const uint2*)&yb[(size_t)(row0 + ar) * D_INNER + k0 + akc];
    zv = *(const uint2*)&projb[(size_t)(row0 + ar) * PROJ_LD + k0 + akc];
  };
  auto writeA = [&](int buf) {
    bf16 ya[4], za[4];
    *(uint2*)ya = yv;
    *(uint2*)za = zv;
    float t[4];
#pragma unroll
    for (int j = 0; j < 4; j++) {
      float z = __bfloat162float(za[j]);
      t[j] = __bfloat162float(ya[j]) * (z / (1.f + expf(-z)));
      ssp += t[j] * t[j];
    }
    bf16 tb[4];
#pragma unroll
    for (int j = 0; j < 4; j++) tb[j] = __float2bfloat16(t[j]);
    *(uint2*)&Ab[buf][ar][akc] = *(uint2*)tb;
  };

  stageB(0, 0);
  loadA(0);
  asm volatile("s_waitcnt vmcnt(0)" ::: "memory");
  writeA(0);
  __syncthreads();

  int cur = 0;
  for (int k0 = 0; k0 < K; k0 += 32, cur ^= 1) {
    bool more = (k0 + 32 < K);
    if (more) { stageB(cur ^ 1, k0 + 32); loadA(k0 + 32); }
    short8 a[2], b[8];
    int kk = (lane >> 4) * 8;
#pragma unroll
    for (int m = 0; m < 2; m++)
      a[m] = *(const short8*)&Ab[cur][m * 16 + (lane & 15)][kk];
#pragma unroll
    for (int n = 0; n < 8; n++)
      b[n] = *(const short8*)&Bb[cur][wc + n * 16 + (lane & 15)][kk];
#pragma unroll
    for (int m = 0; m < 2; m++)
#pragma unroll
      for (int n = 0; n < 8; n++)
        acc[m][n] = __builtin_amdgcn_mfma_f32_16x16x32_bf16(a[m], b[n], acc[m][n], 0, 0, 0);
    if (more) {
      asm volatile("s_waitcnt vmcnt(0)" ::: "memory");
      writeA(cur ^ 1);
    }
    __syncthreads();
  }

  // rms scale per row: ssp covers cols {akc..akc+4} x all k-steps for row ar
#pragma unroll
  for (int o = 1; o < 8; o <<= 1) ssp += __shfl_xor(ssp, o, 8);
  if ((lane & 7) == 0) srow[ar] = rsqrtf(ssp * (1.f / 1024.f) + 1e-5f);
  __syncthreads();

  // epilogue pass 1: v = acc*srow + bias + resid -> xmid; row partial sums
  const int cl = lane & 15, rj = (lane >> 4) * 4;
#pragma unroll
  for (int m = 0; m < 2; m++) {
#pragma unroll
    for (int j = 0; j < 4; j++) {
      int row = m * 16 + rj + j;
      int grow = row0 + row;
      float sr = srow[row];
      float s = 0.f, q = 0.f;
#pragma unroll
      for (int n = 0; n < 8; n++) {
        int col = wc + n * 16 + cl;
        float v = acc[m][n][j] * sr + out_b[col] + x[(size_t)grow * 512 + col];
        acc[m][n][j] = v;
        xmid[(size_t)grow * 512 + col] = v;
        s += v;
        q += v * v;
      }
#pragma unroll
      for (int o = 1; o < 16; o <<= 1) {
        s += __shfl_xor(s, o, 16);
        q += __shfl_xor(q, o, 16);
      }
      if (cl == 0) red[row][wid] = make_float2(s, q);
    }
  }
  __syncthreads();
  // epilogue pass 2: LN2 over the full 512-col row -> xnb (bf16)
#pragma unroll
  for (int m = 0; m < 2; m++) {
#pragma unroll
    for (int j = 0; j < 4; j++) {
      int row = m * 16 + rj + j;
      int grow = row0 + row;
      float2 r0 = red[row][0], r1 = red[row][1], r2 = red[row][2], r3 = red[row][3];
      float sum = r0.x + r1.x + r2.x + r3.x;
      float sq  = r0.y + r1.y + r2.y + r3.y;
      float mean = sum * (1.f / 512.f);
      float var  = sq * (1.f / 512.f) - mean * mean;
      float inv  = rsqrtf(var + 1e-5f);
#pragma unroll
      for (int n = 0; n < 8; n++) {
        int col = wc + n * 16 + cl;
        float xnv = (acc[m][n][j] - mean) * inv * ln2w[col] + ln2b[col];
        xnb[(size_t)grow * 512 + col] = __float2bfloat16(xnv);
      }
    }
  }
}

// ---------------- tree scan (R6): bf16-packed transport ---------------------
__global__ __launch_bounds__(256) void tree_scan_kernel(
    const bf16* __restrict__ xb, const float* __restrict__ aux,
    const int* __restrict__ parent,
    const float* __restrict__ A_log, const float* __restrict__ dt_bias,
    const float* __restrict__ Dp, bf16* __restrict__ y) {
  const int tid = threadIdx.x;
  const int ps = blockIdx.x & 3;
  const int h  = (blockIdx.x >> 2) & 15;
  const int b  = blockIdx.x >> 6;
  const int wid = tid >> 6;
  const int lane = tid & 63;
  const int w = lane >> 2;
  const int q = lane & 3;
  const int pl = wid * 4 + q;

  __shared__ __align__(16) u32   BCs[8][16][20];
  __shared__ __align__(16) float dAs[16][8];
  __shared__ __align__(16) float dtss[16][8];
  __shared__ __align__(16) int   pars[16][8];

  const float Ah  = -expf(A_log[h]);
  const float dtb = dt_bias[h];
  const float Dh  = Dp[h];
  const int xcol = 1024 + (h << 6) + (ps << 4) + pl;
  const int ycol = (h << 6) + (ps << 4) + pl;

  float hst[16];
#pragma unroll
  for (int n = 0; n < 16; n++) hst[n] = 0.f;

  const int sp_t = (tid >> 1) >> 4, sp_w = (tid >> 1) & 15, sp_h = tid & 1;

  for (int c = 0; c < 8; c++) {
    const int t0 = c * 8;
    __syncthreads();
    float xv[8];
#pragma unroll
    for (int tt = 0; tt < 8; tt++) {
      size_t row = ((size_t)(b * NT + t0 + tt)) * NW + w;
      xv[tt] = __bfloat162float(xb[row * PROJ_LD + xcol]);
    }
    if (tid < 128) {
      int t = tid >> 4, wv = tid & 15;
      size_t row = ((size_t)(b * NT + t0 + t)) * NW + wv;
      float dtr = aux[row * 64 + 32 + h] + dtb;
      float dtv = (dtr > 20.f) ? dtr : log1pf(expf(dtr));
      dtss[wv][t] = dtv;
      dAs[wv][t]  = expf(dtv * Ah);
      pars[wv][t] = parent[row];
    }
    {
      size_t row = ((size_t)(b * NT + t0 + sp_t)) * NW + sp_w;
      const float* src = aux + row * 64 + sp_h * 16;
      float4 v0 = *(const float4*)&src[0];
      float4 v1 = *(const float4*)&src[4];
      float4 v2 = *(const float4*)&src[8];
      float4 v3 = *(const float4*)&src[12];
      uint4 p0 = {pack_bf(v0.x, v0.y), pack_bf(v0.z, v0.w),
                  pack_bf(v1.x, v1.y), pack_bf(v1.z, v1.w)};
      uint4 p1 = {pack_bf(v2.x, v2.y), pack_bf(v2.z, v2.w),
                  pack_bf(v3.x, v3.y), pack_bf(v3.z, v3.w)};
      *(uint4*)&BCs[sp_t][sp_w][sp_h * 8]     = p0;
      *(uint4*)&BCs[sp_t][sp_w][sp_h * 8 + 4] = p1;
    }
    __syncthreads();
    float dAr[8], dtr8[8];
    int parr[8];
    *(float4*)&dAr[0]  = *(const float4*)&dAs[w][0];
    *(float4*)&dAr[4]  = *(const float4*)&dAs[w][4];
    *(float4*)&dtr8[0] = *(const float4*)&dtss[w][0];
    *(float4*)&dtr8[4] = *(const float4*)&dtss[w][4];
    *(int4*)&parr[0]   = *(const int4*)&pars[w][0];
    *(int4*)&parr[4]   = *(const int4*)&pars[w][4];

#pragma unroll
    for (int tt = 0; tt < 8; tt++) {
      float dA  = dAr[tt];
      float dtx = dtr8[tt] * xv[tt];
      int   par = parr[tt];
      int gidx = (((par << 2) | q) << 2);
      u32 pk[8];
#pragma unroll
      for (int i = 0; i < 8; i++)
        pk[i] = (u32)__builtin_amdgcn_ds_bpermute(
            gidx, (int)pack_bf(hst[2 * i], hst[2 * i + 1]));
      uint4 bA = *(const uint4*)&BCs[tt][w][0];
      uint4 bB = *(const uint4*)&BCs[tt][w][4];
      uint4 cA = *(const uint4*)&BCs[tt][w][8];
      uint4 cB = *(const uint4*)&BCs[tt][w][12];
      u32 bwv[8] = {bA.x, bA.y, bA.z, bA.w, bB.x, bB.y, bB.z, bB.w};
      u32 cwv[8] = {cA.x, cA.y, cA.z, cA.w, cB.x, cB.y, cB.z, cB.w};
      float yv = 0.f;
#pragma unroll
      for (int i = 0; i < 8; i++) {
        u32 g = pk[i], bu = bwv[i], cu = cwv[i];
        float hp0 = ubits(g << 16),  hp1 = ubits(g & 0xffff0000u);
        float bl  = ubits(bu << 16), bh  = ubits(bu & 0xffff0000u);
        float cl  = ubits(cu << 16), ch  = ubits(cu & 0xffff0000u);
        float h0 = fmaf(dA, hp0, dtx * bl);
        float h1 = fmaf(dA, hp1, dtx * bh);
        hst[2 * i] = h0;
        hst[2 * i + 1] = h1;
        yv = fmaf(h0, cl, fmaf(h1, ch, yv));
      }
      size_t row = ((size_t)(b * NT + t0 + tt)) * NW + w;
      y[row * D_INNER + ycol] = __float2bfloat16(fmaf(Dh, xv[tt], yv));
    }
  }
}

extern "C" void kernel_launch(void* const* d_in, const int* in_sizes, int n_in,
                              void* d_out, int out_size, void* d_ws, size_t ws_size,
                              hipStream_t stream) {
  const float* x       = (const float*)d_in[0];
  const int*   parent  = (const int*)d_in[1];
  const float* ln1_w   = (const float*)d_in[2];
  const float* ln1_b   = (const float*)d_in[3];
  const float* in_w    = (const float*)d_in[4];
  const float* in_b    = (const float*)d_in[5];
  const float* A_log   = (const float*)d_in[6];
  const float* dt_bias = (const float*)d_in[7];
  const float* Dp      = (const float*)d_in[8];
  const float* norm_w  = (const float*)d_in[9];
  const float* out_w   = (const float*)d_in[10];
  const float* out_b   = (const float*)d_in[11];
  const float* ln2_w   = (const float*)d_in[12];
  const float* ln2_b   = (const float*)d_in[13];
  const float* ff1_w   = (const float*)d_in[14];
  const float* ff1_b   = (const float*)d_in[15];
  const float* ff2_w   = (const float*)d_in[16];
  const float* ff2_b   = (const float*)d_in[17];
  float* outp = (float*)d_out;

  char* wp = (char*)d_ws;
  bf16* xnb    = (bf16*)wp;  wp += (size_t)MROWS * D_MODEL * 2;
  bf16* in_wt  = (bf16*)wp;  wp += (size_t)PROJ_LD * D_MODEL * 2;
  bf16* out_wt = (bf16*)wp;  wp += (size_t)D_MODEL * D_INNER * 2;
  bf16* ff1_wt = (bf16*)wp;  wp += (size_t)2048 * D_MODEL * 2;
  bf16* ff2_wt = (bf16*)wp;  wp += (size_t)D_MODEL * D_INNER * 2;
  bf16* projb  = (bf16*)wp;  wp += (size_t)MROWS * PROJ_LD * 2;
  float* aux   = (float*)wp; wp += (size_t)MROWS * 64 * 4;
  bf16* yb     = (bf16*)wp;  wp += (size_t)MROWS * D_INNER * 2;
  float* xmid  = outp;  // d_out doubles as xmid

  dim3 blk(256);
  // 0) all weight converts in one dispatch (out_w scaled by norm_w)
  wconv_all_kernel<<<3136, blk, 0, stream>>>(
      in_w, in_wt, out_w, out_wt, norm_w, ff1_w, ff1_wt, ff2_w, ff2_wt);
  // 1) LN1 -> bf16
  ln512_bf16_kernel<<<MROWS, blk, 0, stream>>>(x, ln1_w, ln1_b, xnb);
  // 2) in-proj GEMM -> projb (bf16) + aux (fp32 B/C/dt)
  inproj_gemm_kernel<<<dim3(PROJ_LD / 128, MROWS / 128), blk, 0, stream>>>(
      xnb, in_wt, in_b, projb, aux, D_MODEL);
  // 3) tree scan -> yb (bf16)
  tree_scan_kernel<<<NB * NHEAD * 4, blk, 0, stream>>>(projb, aux, parent,
                                                       A_log, dt_bias, Dp, yb);
  // 4) fused gate+RMS + out-proj + resid + LN2 -> xmid (=d_out) and xnb
  outproj_fused_kernel<<<MROWS / 32, blk, 0, stream>>>(
      yb, projb, out_wt, out_b, x, ln2_w, ln2_b, xmid, xnb);
  // 5) FF1 GEMM + SiLU gate fused -> yb (reuse)
  ff1_fused_kernel<<<dim3(8, MROWS / 128), blk, 0, stream>>>(
      xnb, ff1_wt, ff1_b, yb, D_MODEL);
  // 6) FF2 GEMM + resid(xmid) -> d_out
  mfma_gemm_kernel<64, 128, 4, 4, 2><<<dim3(D_MODEL / 128, MROWS / 64), blk, 0, stream>>>(
      yb, ff2_wt, ff2_b, D_MODEL, xmid, outp, D_MODEL, D_INNER);
}

// Round 9
// 206.596 us; speedup vs baseline: 1.0824x; 1.0537x over previous
//
#include <hip/hip_runtime.h>
#include <hip/hip_bf16.h>
#include <cmath>

#define D_MODEL 512
#define D_INNER 1024
#define NHEAD 16
#define HDIM 64
#define NSTATE 16
#define NB 8
#define NT 64
#define NW 16
#define MROWS 8192      // NB*NT*NW
#define PROJ_LD 2176    // padded 2096 -> 17*128
#define NPROJ 2096

typedef __attribute__((ext_vector_type(8))) short short8;
typedef __attribute__((ext_vector_type(4))) float f32x4;
typedef __hip_bfloat16 bf16;
typedef unsigned int u32;

__device__ __forceinline__ u32 fbits(float f) { return __float_as_uint(f); }
__device__ __forceinline__ float ubits(u32 u) { return __uint_as_float(u); }
__device__ __forceinline__ u32 pack_bf(float a, float b) {
  return (fbits(b) & 0xffff0000u) | (fbits(a) >> 16);
}

// counted vmcnt wait (literal immediates; "memory" clobber = compiler fence)
template<int N> __device__ __forceinline__ void vmwait() {
  if constexpr (N == 0)      asm volatile("s_waitcnt vmcnt(0)" ::: "memory");
  else if constexpr (N == 2) asm volatile("s_waitcnt vmcnt(2)" ::: "memory");
  else if constexpr (N == 3) asm volatile("s_waitcnt vmcnt(3)" ::: "memory");
  else if constexpr (N == 4) asm volatile("s_waitcnt vmcnt(4)" ::: "memory");
  else if constexpr (N == 6) asm volatile("s_waitcnt vmcnt(6)" ::: "memory");
  else if constexpr (N == 8) asm volatile("s_waitcnt vmcnt(8)" ::: "memory");
  else static_assert(N == 0, "unsupported vmcnt");
}

// ---------------- block-wide sum reduction (256 threads = 4 waves) ----------
__device__ __forceinline__ float block_sum(float v, float* sbuf) {
#pragma unroll
  for (int o = 32; o > 0; o >>= 1) v += __shfl_down(v, o, 64);
  int lane = threadIdx.x & 63, wid = threadIdx.x >> 6;
  if (lane == 0) sbuf[wid] = v;
  __syncthreads();
  if (threadIdx.x == 0) {
    float t = 0.f;
    for (int i = 0; i < 4; i++) t += sbuf[i];
    sbuf[0] = t;
  }
  __syncthreads();
  return sbuf[0];
}

// ---------------- LayerNorm over 512, bf16 out ------------------------------
__global__ __launch_bounds__(256) void ln512_bf16_kernel(
    const float* __restrict__ x, const float* __restrict__ w,
    const float* __restrict__ b, bf16* __restrict__ out) {
  __shared__ float s1[8], s2[8];
  int row = blockIdx.x;
  const float* xr = x + (size_t)row * D_MODEL;
  bf16* outr = out + (size_t)row * D_MODEL;
  int c0 = threadIdx.x, c1 = threadIdx.x + 256;
  float v0 = xr[c0], v1 = xr[c1];
  float s  = block_sum(v0 + v1, s1);
  float ss = block_sum(v0 * v0 + v1 * v1, s2);
  float mean = s * (1.f / 512.f);
  float var  = ss * (1.f / 512.f) - mean * mean;
  float inv  = rsqrtf(var + 1e-5f);
  outr[c0] = __float2bfloat16((v0 - mean) * inv * w[c0] + b[c0]);
  outr[c1] = __float2bfloat16((v1 - mean) * inv * w[c1] + b[c1]);
}

// ---------------- merged weight convert+transpose (4 configs in 1 grid) -----
__global__ __launch_bounds__(256) void wconv_all_kernel(
    const float* __restrict__ in_w, bf16* __restrict__ in_wt,
    const float* __restrict__ out_w, bf16* __restrict__ out_wt,
    const float* __restrict__ ff1_w, bf16* __restrict__ ff1_wt,
    const float* __restrict__ ff2_w, bf16* __restrict__ ff2_wt) {
  __shared__ float tile[32][33];
  int id = blockIdx.x;
  const float* w; bf16* wt;
  int K, N, Npad, bx, by;
  if (id < 1088)      { w = in_w;  wt = in_wt;  K = 512;  N = NPROJ; Npad = PROJ_LD; bx = id % 68;  by = id / 68; }
  else if (id < 1600) { int j = id - 1088; w = out_w; wt = out_wt; K = 1024; N = 512;  Npad = 512;  bx = j % 16; by = j / 16; }
  else if (id < 2624) { int j = id - 1600; w = ff1_w; wt = ff1_wt; K = 512;  N = 2048; Npad = 2048; bx = j % 64; by = j / 64; }
  else                { int j = id - 2624; w = ff2_w; wt = ff2_wt; K = 1024; N = 512;  Npad = 512;  bx = j % 16; by = j / 16; }
  int n0 = bx * 32, k0 = by * 32;
  int tx = threadIdx.x & 31, ty = threadIdx.x >> 5;  // 32 x 8
#pragma unroll
  for (int i = 0; i < 4; i++) {
    int k = k0 + ty + i * 8, n = n0 + tx;
    tile[ty + i * 8][tx] = (k < K && n < N) ? w[(size_t)k * N + n] : 0.f;
  }
  __syncthreads();
#pragma unroll
  for (int i = 0; i < 4; i++) {
    int n = n0 + ty + i * 8, k = k0 + tx;
    if (n < Npad && k < K)
      wt[(size_t)n * K + k] = __float2bfloat16(tile[tx][ty + i * 8]);
  }
}

// ---------------- fp32-out MFMA GEMM, 3-buffer counted-vmcnt pipeline -------
template<int BM, int BN, int WN, int MR, int NR>
__global__ __launch_bounds__(256) void mfma_gemm_kernel(
    const bf16* __restrict__ A, const bf16* __restrict__ Bt,
    const float* __restrict__ bias, int nbias,
    const float* __restrict__ resid,
    float* __restrict__ C, int ldc, int K) {
  constexpr int ROWS = BM + BN;
  constexpr int ISS  = ROWS / 64;
  __shared__ __align__(16) bf16 sAB[3][ROWS][32];

  int wid = threadIdx.x >> 6, lane = threadIdx.x & 63;
  int row0 = blockIdx.y * BM, col0 = blockIdx.x * BN;
  int wr = (wid / WN) * (MR * 16);
  int wc = (wid % WN) * (NR * 16);
  int lr = lane >> 2;
  int lc = (lane & 3) * 8;

  f32x4 acc[MR][NR];
#pragma unroll
  for (int m = 0; m < MR; m++)
#pragma unroll
    for (int n = 0; n < NR; n++) acc[m][n] = (f32x4){0.f, 0.f, 0.f, 0.f};

  auto stage = [&](int buf, int k0) {
#pragma unroll
    for (int i = 0; i < ISS; i++) {
      int rb = (wid * ISS + i) * 16;
      int r = rb + lr;
      const bf16* src = (r < BM)
          ? A  + (size_t)(row0 + r) * K + k0 + lc
          : Bt + (size_t)(col0 + (r - BM)) * K + k0 + lc;
      __builtin_amdgcn_global_load_lds(
          (const __attribute__((address_space(1))) void*)src,
          (__attribute__((address_space(3))) void*)&sAB[buf][rb][0], 16, 0, 0);
    }
  };

  stage(0, 0);
  stage(1, 32);
  int cur = 0;
  for (int k0 = 0; k0 < K; k0 += 32) {
    if (k0 + 32 < K) vmwait<ISS>(); else vmwait<0>();
    __builtin_amdgcn_s_barrier();
    asm volatile("" ::: "memory");
    if (k0 + 64 < K) stage(cur == 0 ? 2 : cur - 1, k0 + 64);
    short8 a[MR], b[NR];
    int kk = (lane >> 4) * 8;
#pragma unroll
    for (int m = 0; m < MR; m++)
      a[m] = *(const short8*)&sAB[cur][wr + m * 16 + (lane & 15)][kk];
#pragma unroll
    for (int n = 0; n < NR; n++)
      b[n] = *(const short8*)&sAB[cur][BM + wc + n * 16 + (lane & 15)][kk];
#pragma unroll
    for (int m = 0; m < MR; m++)
#pragma unroll
      for (int n = 0; n < NR; n++)
        acc[m][n] = __builtin_amdgcn_mfma_f32_16x16x32_bf16(a[m], b[n], acc[m][n], 0, 0, 0);
    asm volatile("" ::: "memory");
    cur = (cur == 2) ? 0 : cur + 1;
  }

  int crow = row0 + wr + (lane >> 4) * 4;
  int ccol = col0 + wc + (lane & 15);
#pragma unroll
  for (int m = 0; m < MR; m++) {
#pragma unroll
    for (int n = 0; n < NR; n++) {
      int colg = ccol + n * 16;
      float bv = bias ? ((colg < nbias) ? bias[colg] : 0.f) : 0.f;
#pragma unroll
      for (int j = 0; j < 4; j++) {
        int rowg = crow + m * 16 + j;
        float v = acc[m][n][j] + bv;
        if (resid) v += resid[(size_t)rowg * ldc + colg];
        C[(size_t)rowg * ldc + colg] = v;
      }
    }
  }
}

// ---------------- in-proj GEMM (3-buf pipeline): bf16 out + fp32 aux --------
__global__ __launch_bounds__(256) void inproj_gemm_kernel(
    const bf16* __restrict__ A, const bf16* __restrict__ Bt,
    const float* __restrict__ bias,
    bf16* __restrict__ Cb, float* __restrict__ aux, int K) {
  constexpr int BM = 128, ROWS = 256, ISS = 4;
  __shared__ __align__(16) bf16 sAB[3][ROWS][32];

  int wid = threadIdx.x >> 6, lane = threadIdx.x & 63;
  int row0 = blockIdx.y * BM, col0 = blockIdx.x * 128;
  int wr = (wid >> 1) * 64;
  int wc = (wid & 1) * 64;
  int lr = lane >> 2;
  int lc = (lane & 3) * 8;

  f32x4 acc[4][4];
#pragma unroll
  for (int m = 0; m < 4; m++)
#pragma unroll
    for (int n = 0; n < 4; n++) acc[m][n] = (f32x4){0.f, 0.f, 0.f, 0.f};

  auto stage = [&](int buf, int k0) {
#pragma unroll
    for (int i = 0; i < ISS; i++) {
      int rb = (wid * ISS + i) * 16;
      int r = rb + lr;
      const bf16* src = (r < BM)
          ? A  + (size_t)(row0 + r) * K + k0 + lc
          : Bt + (size_t)(col0 + (r - BM)) * K + k0 + lc;
      __builtin_amdgcn_global_load_lds(
          (const __attribute__((address_space(1))) void*)src,
          (__attribute__((address_space(3))) void*)&sAB[buf][rb][0], 16, 0, 0);
    }
  };

  stage(0, 0);
  stage(1, 32);
  int cur = 0;
  for (int k0 = 0; k0 < K; k0 += 32) {
    if (k0 + 32 < K) vmwait<ISS>(); else vmwait<0>();
    __builtin_amdgcn_s_barrier();
    asm volatile("" ::: "memory");
    if (k0 + 64 < K) stage(cur == 0 ? 2 : cur - 1, k0 + 64);
    short8 a[4], b[4];
    int kk = (lane >> 4) * 8;
#pragma unroll
    for (int m = 0; m < 4; m++)
      a[m] = *(const short8*)&sAB[cur][wr + m * 16 + (lane & 15)][kk];
#pragma unroll
    for (int n = 0; n < 4; n++)
      b[n] = *(const short8*)&sAB[cur][BM + wc + n * 16 + (lane & 15)][kk];
#pragma unroll
    for (int m = 0; m < 4; m++)
#pragma unroll
      for (int n = 0; n < 4; n++)
        acc[m][n] = __builtin_amdgcn_mfma_f32_16x16x32_bf16(a[m], b[n], acc[m][n], 0, 0, 0);
    asm volatile("" ::: "memory");
    cur = (cur == 2) ? 0 : cur + 1;
  }

  int crow = row0 + wr + (lane >> 4) * 4;
  int ccol = col0 + wc + (lane & 15);
#pragma unroll
  for (int m = 0; m < 4; m++) {
#pragma unroll
    for (int n = 0; n < 4; n++) {
      int colg = ccol + n * 16;
      float bv = (colg < NPROJ) ? bias[colg] : 0.f;
#pragma unroll
      for (int j = 0; j < 4; j++) {
        int rowg = crow + m * 16 + j;
        float v = acc[m][n][j] + bv;
        Cb[(size_t)rowg * PROJ_LD + colg] = __float2bfloat16(v);
        if (colg >= 2048 && colg < 2112)
          aux[(size_t)rowg * 64 + (colg - 2048)] = v;
      }
    }
  }
}

// ---------------- FF1 GEMM + SiLU gate (3-buf pipeline) -> bf16 -------------
__global__ __launch_bounds__(256) void ff1_fused_kernel(
    const bf16* __restrict__ A, const bf16* __restrict__ Bt,
    const float* __restrict__ bias, bf16* __restrict__ out, int K) {
  constexpr int BM = 128, ROWS = 384, ISS = 6;
  __shared__ __align__(16) bf16 sAB[3][ROWS][32];

  int wid = threadIdx.x >> 6, lane = threadIdx.x & 63;
  int row0 = blockIdx.y * BM, col0 = blockIdx.x * 128;
  int wr = (wid >> 1) * 64;
  int wc = (wid & 1) * 64;
  int lr = lane >> 2;
  int lc = (lane & 3) * 8;

  f32x4 acc1[4][4], acc2[4][4];
#pragma unroll
  for (int m = 0; m < 4; m++)
#pragma unroll
    for (int n = 0; n < 4; n++) {
      acc1[m][n] = (f32x4){0.f, 0.f, 0.f, 0.f};
      acc2[m][n] = (f32x4){0.f, 0.f, 0.f, 0.f};
    }

  auto stage = [&](int buf, int k0) {
#pragma unroll
    for (int i = 0; i < ISS; i++) {
      int rb = (wid * ISS + i) * 16;
      int r = rb + lr;
      const bf16* src;
      if (r < BM)       src = A  + (size_t)(row0 + r) * K + k0 + lc;
      else if (r < 256) src = Bt + (size_t)(col0 + (r - 128)) * K + k0 + lc;
      else              src = Bt + (size_t)(1024 + col0 + (r - 256)) * K + k0 + lc;
      __builtin_amdgcn_global_load_lds(
          (const __attribute__((address_space(1))) void*)src,
          (__attribute__((address_space(3))) void*)&sAB[buf][rb][0], 16, 0, 0);
    }
  };

  stage(0, 0);
  stage(1, 32);
  int cur = 0;
  for (int k0 = 0; k0 < K; k0 += 32) {
    if (k0 + 32 < K) vmwait<ISS>(); else vmwait<0>();
    __builtin_amdgcn_s_barrier();
    asm volatile("" ::: "memory");
    if (k0 + 64 < K) stage(cur == 0 ? 2 : cur - 1, k0 + 64);
    short8 a[4], b1[4], b2[4];
    int kk = (lane >> 4) * 8;
#pragma unroll
    for (int m = 0; m < 4; m++)
      a[m] = *(const short8*)&sAB[cur][wr + m * 16 + (lane & 15)][kk];
#pragma unroll
    for (int n = 0; n < 4; n++) {
      b1[n] = *(const short8*)&sAB[cur][128 + wc + n * 16 + (lane & 15)][kk];
      b2[n] = *(const short8*)&sAB[cur][256 + wc + n * 16 + (lane & 15)][kk];
    }
#pragma unroll
    for (int m = 0; m < 4; m++)
#pragma unroll
      for (int n = 0; n < 4; n++) {
        acc1[m][n] = __builtin_amdgcn_mfma_f32_16x16x32_bf16(a[m], b1[n], acc1[m][n], 0, 0, 0);
        acc2[m][n] = __builtin_amdgcn_mfma_f32_16x16x32_bf16(a[m], b2[n], acc2[m][n], 0, 0, 0);
      }
    asm volatile("" ::: "memory");
    cur = (cur == 2) ? 0 : cur + 1;
  }

  int crow = row0 + wr + (lane >> 4) * 4;
  int ccol = col0 + wc + (lane & 15);
#pragma unroll
  for (int m = 0; m < 4; m++) {
#pragma unroll
    for (int n = 0; n < 4; n++) {
      int colg = ccol + n * 16;
      float bv1 = bias[colg];
      float bv2 = bias[1024 + colg];
#pragma unroll
      for (int j = 0; j < 4; j++) {
        int rowg = crow + m * 16 + j;
        float f1 = acc1[m][n][j] + bv1;
        float g  = acc2[m][n][j] + bv2;
        float sg = g / (1.f + expf(-g));
        out[(size_t)rowg * 1024 + colg] = __float2bfloat16(f1 * sg);
      }
    }
  }
}

// ---------------- tree scan (R6): bf16-packed transport ---------------------
__global__ __launch_bounds__(256) void tree_scan_kernel(
    const bf16* __restrict__ xb, const float* __restrict__ aux,
    const int* __restrict__ parent,
    const float* __restrict__ A_log, const float* __restrict__ dt_bias,
    const float* __restrict__ Dp, bf16* __restrict__ y) {
  const int tid = threadIdx.x;
  const int ps = blockIdx.x & 3;
  const int h  = (blockIdx.x >> 2) & 15;
  const int b  = blockIdx.x >> 6;
  const int wid = tid >> 6;
  const int lane = tid & 63;
  const int w = lane >> 2;
  const int q = lane & 3;
  const int pl = wid * 4 + q;

  __shared__ __align__(16) u32   BCs[8][16][20];
  __shared__ __align__(16) float dAs[16][8];
  __shared__ __align__(16) float dtss[16][8];
  __shared__ __align__(16) int   pars[16][8];

  const float Ah  = -expf(A_log[h]);
  const float dtb = dt_bias[h];
  const float Dh  = Dp[h];
  const int xcol = 1024 + (h << 6) + (ps << 4) + pl;
  const int ycol = (h << 6) + (ps << 4) + pl;

  float hst[16];
#pragma unroll
  for (int n = 0; n < 16; n++) hst[n] = 0.f;

  const int sp_t = (tid >> 1) >> 4, sp_w = (tid >> 1) & 15, sp_h = tid & 1;

  for (int c = 0; c < 8; c++) {
    const int t0 = c * 8;
    __syncthreads();
    float xv[8];
#pragma unroll
    for (int tt = 0; tt < 8; tt++) {
      size_t row = ((size_t)(b * NT + t0 + tt)) * NW + w;
      xv[tt] = __bfloat162float(xb[row * PROJ_LD + xcol]);
    }
    if (tid < 128) {
      int t = tid >> 4, wv = tid & 15;
      size_t row = ((size_t)(b * NT + t0 + t)) * NW + wv;
      float dtr = aux[row * 64 + 32 + h] + dtb;
      float dtv = (dtr > 20.f) ? dtr : log1pf(expf(dtr));
      dtss[wv][t] = dtv;
      dAs[wv][t]  = expf(dtv * Ah);
      pars[wv][t] = parent[row];
    }
    {
      size_t row = ((size_t)(b * NT + t0 + sp_t)) * NW + sp_w;
      const float* src = aux + row * 64 + sp_h * 16;
      float4 v0 = *(const float4*)&src[0];
      float4 v1 = *(const float4*)&src[4];
      float4 v2 = *(const float4*)&src[8];
      float4 v3 = *(const float4*)&src[12];
      uint4 p0 = {pack_bf(v0.x, v0.y), pack_bf(v0.z, v0.w),
                  pack_bf(v1.x, v1.y), pack_bf(v1.z, v1.w)};
      uint4 p1 = {pack_bf(v2.x, v2.y), pack_bf(v2.z, v2.w),
                  pack_bf(v3.x, v3.y), pack_bf(v3.z, v3.w)};
      *(uint4*)&BCs[sp_t][sp_w][sp_h * 8]     = p0;
      *(uint4*)&BCs[sp_t][sp_w][sp_h * 8 + 4] = p1;
    }
    __syncthreads();
    float dAr[8], dtr8[8];
    int parr[8];
    *(float4*)&dAr[0]  = *(const float4*)&dAs[w][0];
    *(float4*)&dAr[4]  = *(const float4*)&dAs[w][4];
    *(float4*)&dtr8[0] = *(const float4*)&dtss[w][0];
    *(float4*)&dtr8[4] = *(const float4*)&dtss[w][4];
    *(int4*)&parr[0]   = *(const int4*)&pars[w][0];
    *(int4*)&parr[4]   = *(const int4*)&pars[w][4];

#pragma unroll
    for (int tt = 0; tt < 8; tt++) {
      float dA  = dAr[tt];
      float dtx = dtr8[tt] * xv[tt];
      int   par = parr[tt];
      int gidx = (((par << 2) | q) << 2);
      u32 pk[8];
#pragma unroll
      for (int i = 0; i < 8; i++)
        pk[i] = (u32)__builtin_amdgcn_ds_bpermute(
            gidx, (int)pack_bf(hst[2 * i], hst[2 * i + 1]));
      uint4 bA = *(const uint4*)&BCs[tt][w][0];
      uint4 bB = *(const uint4*)&BCs[tt][w][4];
      uint4 cA = *(const uint4*)&BCs[tt][w][8];
      uint4 cB = *(const uint4*)&BCs[tt][w][12];
      u32 bwv[8] = {bA.x, bA.y, bA.z, bA.w, bB.x, bB.y, bB.z, bB.w};
      u32 cwv[8] = {cA.x, cA.y, cA.z, cA.w, cB.x, cB.y, cB.z, cB.w};
      float yv = 0.f;
#pragma unroll
      for (int i = 0; i < 8; i++) {
        u32 g = pk[i], bu = bwv[i], cu = cwv[i];
        float hp0 = ubits(g << 16),  float_hp1_dummy;
        (void)float_hp1_dummy;
        float hp1 = ubits(g & 0xffff0000u);
        float bl  = ubits(bu << 16), bh  = ubits(bu & 0xffff0000u);
        float cl  = ubits(cu << 16), ch  = ubits(cu & 0xffff0000u);
        float h0 = fmaf(dA, hp0, dtx * bl);
        float h1 = fmaf(dA, hp1, dtx * bh);
        hst[2 * i] = h0;
        hst[2 * i + 1] = h1;
        yv = fmaf(h0, cl, fmaf(h1, ch, yv));
      }
      size_t row = ((size_t)(b * NT + t0 + tt)) * NW + w;
      y[row * D_INNER + ycol] = __float2bfloat16(fmaf(Dh, xv[tt], yv));
    }
  }
}

// ---------------- gated RMSNorm (bf16 in/out) -------------------------------
__global__ __launch_bounds__(256) void gate_rms_kernel(
    const bf16* __restrict__ yin, const bf16* __restrict__ projb,
    const float* __restrict__ norm_w, bf16* __restrict__ out) {
  __shared__ float sbuf[8];
  int row = blockIdx.x;
  const bf16* yr = yin + (size_t)row * D_INNER;
  const bf16* zr = projb + (size_t)row * PROJ_LD;  // z = cols [0,1024)
  int c = threadIdx.x * 4;
  bf16 y4[4], z4[4];
  *(uint2*)y4 = *(const uint2*)&yr[c];
  *(uint2*)z4 = *(const uint2*)&zr[c];
  float gv[4];
  float ss = 0.f;
#pragma unroll
  for (int j = 0; j < 4; j++) {
    float z = __bfloat162float(z4[j]);
    float t = __bfloat162float(y4[j]) * (z / (1.f + expf(-z)));
    gv[j] = t;
    ss += t * t;
  }
  ss = block_sum(ss, sbuf);
  float scale = rsqrtf(ss * (1.f / 1024.f) + 1e-5f);
  bf16 o4[4];
#pragma unroll
  for (int j = 0; j < 4; j++) o4[j] = __float2bfloat16(gv[j] * scale * norm_w[c + j]);
  *(uint2*)&out[(size_t)row * D_INNER + c] = *(uint2*)o4;
}

extern "C" void kernel_launch(void* const* d_in, const int* in_sizes, int n_in,
                              void* d_out, int out_size, void* d_ws, size_t ws_size,
                              hipStream_t stream) {
  const float* x       = (const float*)d_in[0];
  const int*   parent  = (const int*)d_in[1];
  const float* ln1_w   = (const float*)d_in[2];
  const float* ln1_b   = (const float*)d_in[3];
  const float* in_w    = (const float*)d_in[4];
  const float* in_b    = (const float*)d_in[5];
  const float* A_log   = (const float*)d_in[6];
  const float* dt_bias = (const float*)d_in[7];
  const float* Dp      = (const float*)d_in[8];
  const float* norm_w  = (const float*)d_in[9];
  const float* out_w   = (const float*)d_in[10];
  const float* out_b   = (const float*)d_in[11];
  const float* ln2_w   = (const float*)d_in[12];
  const float* ln2_b   = (const float*)d_in[13];
  const float* ff1_w   = (const float*)d_in[14];
  const float* ff1_b   = (const float*)d_in[15];
  const float* ff2_w   = (const float*)d_in[16];
  const float* ff2_b   = (const float*)d_in[17];
  float* outp = (float*)d_out;

  char* wp = (char*)d_ws;
  bf16* xnb    = (bf16*)wp;  wp += (size_t)MROWS * D_MODEL * 2;
  bf16* in_wt  = (bf16*)wp;  wp += (size_t)PROJ_LD * D_MODEL * 2;
  bf16* out_wt = (bf16*)wp;  wp += (size_t)D_MODEL * D_INNER * 2;
  bf16* ff1_wt = (bf16*)wp;  wp += (size_t)2048 * D_MODEL * 2;
  bf16* ff2_wt = (bf16*)wp;  wp += (size_t)D_MODEL * D_INNER * 2;
  bf16* projb  = (bf16*)wp;  wp += (size_t)MROWS * PROJ_LD * 2;
  float* aux   = (float*)wp; wp += (size_t)MROWS * 64 * 4;
  bf16* yb     = (bf16*)wp;  wp += (size_t)MROWS * D_INNER * 2;
  bf16* ygb    = (bf16*)wp;  wp += (size_t)MROWS * D_INNER * 2;
  float* xmid  = outp;  // d_out doubles as xmid

  dim3 blk(256);
  // 0) all weight converts in one dispatch
  wconv_all_kernel<<<3136, blk, 0, stream>>>(
      in_w, in_wt, out_w, out_wt, ff1_w, ff1_wt, ff2_w, ff2_wt);
  // 1) LN1 -> bf16
  ln512_bf16_kernel<<<MROWS, blk, 0, stream>>>(x, ln1_w, ln1_b, xnb);
  // 2) in-proj GEMM -> projb (bf16) + aux (fp32 B/C/dt)
  inproj_gemm_kernel<<<dim3(PROJ_LD / 128, MROWS / 128), blk, 0, stream>>>(
      xnb, in_wt, in_b, projb, aux, D_MODEL);
  // 3) tree scan -> yb (bf16)
  tree_scan_kernel<<<NB * NHEAD * 4, blk, 0, stream>>>(projb, aux, parent,
                                                       A_log, dt_bias, Dp, yb);
  // 4) gated RMSNorm -> ygb (bf16)
  gate_rms_kernel<<<MROWS, blk, 0, stream>>>(yb, projb, norm_w, ygb);
  // 5) out-proj GEMM + resid(x) -> xmid (fp32)
  mfma_gemm_kernel<64, 128, 4, 4, 2><<<dim3(D_MODEL / 128, MROWS / 64), blk, 0, stream>>>(
      ygb, out_wt, out_b, D_MODEL, x, xmid, D_MODEL, D_INNER);
  // 6) LN2 -> xnb
  ln512_bf16_kernel<<<MROWS, blk, 0, stream>>>(xmid, ln2_w, ln2_b, xnb);
  // 7) FF1 GEMM + SiLU gate fused -> yb (reuse)
  ff1_fused_kernel<<<dim3(8, MROWS / 128), blk, 0, stream>>>(
      xnb, ff1_wt, ff1_b, yb, D_MODEL);
  // 8) FF2 GEMM + resid(xmid) -> d_out
  mfma_gemm_kernel<64, 128, 4, 4, 2><<<dim3(D_MODEL / 128, MROWS / 64), blk, 0, stream>>>(
      yb, ff2_wt, ff2_b, D_MODEL, xmid, outp, D_MODEL, D_INNER);
}